// Round 12
// baseline (17081.351 us; speedup 1.0000x reference)
//
#include <hip/hip_runtime.h>
#include <hip/hip_bf16.h>
#include <cstdint>

#define B_ 64
#define T_ 1024
#define D_ 512
#define H_ 1024

typedef unsigned short u16;
typedef unsigned long long u64;
typedef __attribute__((ext_vector_type(4))) float f32x4;
typedef __attribute__((ext_vector_type(8))) short bf16x8;   // 8 bf16 in 4 VGPRs
typedef __attribute__((ext_vector_type(8))) u16 u16x8;

#define VMWAIT(N) do { asm volatile("s_waitcnt vmcnt(" #N ")" ::: "memory"); \
                       __builtin_amdgcn_sched_barrier(0); } while (0)

__device__ __forceinline__ u16 f2bf(float f) {
    uint32_t u = __float_as_uint(f);
    uint32_t r = (u + 0x7FFFu + ((u >> 16) & 1u)) >> 16;   // RNE
    return (u16)r;
}
__device__ __forceinline__ float sigm(float x)  { return 1.f / (1.f + __expf(-x)); }
__device__ __forceinline__ float ftanh(float x) { return 1.f - 2.f / (__expf(2.f * x) + 1.f); }

// ---- W [K][N] fp32 -> WT [N][dstLD] bf16 at column offset koff ----
__global__ __launch_bounds__(256) void transp(const float* __restrict__ src, u16* __restrict__ dst,
                                              int N, int dstLD, int koff) {
    __shared__ float tile[32][33];
    int n0 = blockIdx.x * 32, k0 = blockIdx.y * 32;
    int tx = threadIdx.x, ty = threadIdx.y;   // 32 x 8
    #pragma unroll
    for (int i = 0; i < 4; ++i)
        tile[ty + 8 * i][tx] = src[(size_t)(k0 + ty + 8 * i) * N + n0 + tx];
    __syncthreads();
    #pragma unroll
    for (int i = 0; i < 4; ++i) {
        int n = n0 + ty + 8 * i;
        dst[(size_t)n * dstLD + koff + k0 + tx] = f2bf(tile[tx][ty + 8 * i]);
    }
}

// 16 dwordx4 f32 loads = 8 fragments of 8 floats, plain cached
__device__ __forceinline__ void ldx16(f32x4* s, const float* p) {
    #pragma unroll
    for (int j = 0; j < 8; ++j) {
        const float* pj = p + j * 32;
        asm volatile("global_load_dwordx4 %0, %2, off\n\t"
                     "global_load_dwordx4 %1, %2, off offset:16"
                     : "=&v"(s[2 * j]), "=&v"(s[2 * j + 1]) : "v"(pj));
    }
}
__device__ __forceinline__ bf16x8 cvt8(f32x4 a, f32x4 b) {
    union { u16x8 u; bf16x8 v; } r;
    r.u[0] = f2bf(a[0]); r.u[1] = f2bf(a[1]); r.u[2] = f2bf(a[2]); r.u[3] = f2bf(a[3]);
    r.u[4] = f2bf(b[0]); r.u[5] = f2bf(b[1]); r.u[6] = f2bf(b[2]); r.u[7] = f2bf(b[3]);
    return r.v;
}
// 8 h-fragments, octet-major (stride 4096B), coherent (MALL-direct)
__device__ __forceinline__ void ld8_oct(bf16x8* s, const u16* base) {
    #pragma unroll
    for (int j = 0; j < 8; ++j) {
        const u16* pj = base + j * 2048;
        asm volatile("global_load_dwordx4 %0, %1, off sc0 sc1" : "=&v"(s[j]) : "v"(pj));
    }
}

// generic MFMA chunk: weight-column byte-bases cb0/cb1, k-byte base kb0
__device__ __forceinline__ void mfma2(const bf16x8* st, const char* lds, int cb0, int cb1,
                                      int kb0, int sw, f32x4& acc0, f32x4& acc1) {
    #pragma unroll
    for (int j = 0; j < 8; ++j) {
        const int kb = kb0 + j * 64;
        bf16x8 w0 = *reinterpret_cast<const bf16x8*>(lds + ((cb0 + kb) ^ sw));
        bf16x8 w1 = *reinterpret_cast<const bf16x8*>(lds + ((cb1 + kb) ^ sw));
        acc0 = __builtin_amdgcn_mfma_f32_16x16x32_bf16(st[j], w0, acc0, 0, 0, 0);
        acc1 = __builtin_amdgcn_mfma_f32_16x16x32_bf16(st[j], w1, acc1, 0, 0, 0);
    }
}

// wave-wide poll over 128 flags (64 lanes x u64)
__device__ __forceinline__ void pollge(const u64* q, int t) {
    if (t <= 0) return;
    for (;;) {
        u64 v = __hip_atomic_load(q, __ATOMIC_RELAXED, __HIP_MEMORY_SCOPE_AGENT);
        bool ok = ((int)(unsigned)v >= t) && ((int)(unsigned)(v >> 32) >= t);
        if (__all(ok)) break;
        __builtin_amdgcn_s_sleep(1);
    }
    __builtin_amdgcn_sched_barrier(0);
}
// wave-wide poll over 64 flags (lanes 0-31; upper lanes duplicate)
__device__ __forceinline__ void pollge32(const u64* q, int t, int lane) {
    if (t <= 0) return;
    const u64* ql = q + (lane & 31);
    for (;;) {
        u64 v = __hip_atomic_load(ql, __ATOMIC_RELAXED, __HIP_MEMORY_SCOPE_AGENT);
        bool ok = ((int)(unsigned)v >= t) && ((int)(unsigned)(v >> 32) >= t);
        if (__all(ok)) break;
        __builtin_amdgcn_s_sleep(1);
    }
    __builtin_amdgcn_sched_barrier(0);
}

// ============ persistent fused 2-layer LSTM, K-split L1 ============
// bid 0..127: L0 (8 h-cols, K=1536). bid 128..191: K0 j (16 h-cols, K=h0 1024, partials).
// bid 192..255: K1 j (16 h-cols, K=h1 1024, combine+pointwise+publish h1/y/finals).
extern "C" __global__ void __launch_bounds__(512, 2) lstm_persist(
    const float* __restrict__ x, const u16* __restrict__ Wx0T,
    const u16* __restrict__ WT0, const u16* __restrict__ WT1,
    const float* __restrict__ b0, const float* __restrict__ b1,
    unsigned int* __restrict__ l0f, unsigned int* __restrict__ l1f,
    unsigned int* __restrict__ pf,
    u16* __restrict__ h0w, u16* __restrict__ h1w,
    float* __restrict__ prt, float* __restrict__ out)
{
    extern __shared__ char lds[];
    const int tid = threadIdx.x;
    const int bid = blockIdx.x;
    const bool isL0 = bid < 128;
    const bool isK1 = bid >= 192;
    const int j = isL0 ? 0 : (bid - 128) & 63;
    const int WB = isL0 ? 32 * 3072 : 64 * 2048;
    float* scr = (float*)(lds + WB);                  // L0: [2][64][36]; K1: [64][76]
    u16* hstg = (u16*)(lds + WB + 19456);

    const int wave = tid >> 6, lane = tid & 63;
    const int r16 = lane & 15, kg = lane >> 4;
    const int m  = wave & 3;
    const int sub = wave >> 2;                        // L0: K-half; K: N-half
    const int rowA = m * 16 + r16;
    const int sw = ((r16 & 7) << 4);
    const int BH = B_ * H_;
    const size_t BTH = (size_t)B_ * T_ * H_;

    // ---- stage weights into LDS (XOR-swizzled) ----
    if (isL0) {
        const int bh = bid * 8;
        for (int idx = tid; idx < 32 * 192; idx += 512) {
            const int c = idx / 192, ko = idx - c * 192;
            const int n = (c & 3) * H_ + bh + (c >> 2);
            const int k = ko * 8;
            u16x8 v;
            if (k < 512) v = *reinterpret_cast<const u16x8*>(Wx0T + (size_t)n * 512  + k);
            else         v = *reinterpret_cast<const u16x8*>(WT0  + (size_t)n * 1024 + (k - 512));
            int byte = c * 3072 + k * 2;
            byte ^= ((c & 7) << 4);
            *reinterpret_cast<u16x8*>(lds + byte) = v;
        }
    } else {
        const int koff = isK1 ? 1024 : 0;
        for (int idx = tid; idx < 64 * 128; idx += 512) {
            const int c = idx >> 7, ko = idx & 127;
            const int n = (c & 3) * H_ + 16 * j + (c >> 2);
            const int k = ko * 8;
            u16x8 v = *reinterpret_cast<const u16x8*>(WT1 + (size_t)n * 2048 + koff + k);
            int byte = c * 2048 + k * 2;
            byte ^= ((c & 7) << 4);
            *reinterpret_cast<u16x8*>(lds + byte) = v;
        }
    }

    float bvA[4], bvB[4];
    float creg0 = 0.f, creg1 = 0.f;
    const int prow = tid >> 3, ph = tid & 7;
    if (isL0) {
        const int nc = bid * 8 + ph;
        bvA[0] = b0[nc]; bvA[1] = b0[H_ + nc]; bvA[2] = b0[2 * H_ + nc]; bvA[3] = b0[3 * H_ + nc];
    } else if (isK1) {
        const int hl0 = 16 * j + 2 * ph;
        #pragma unroll
        for (int g = 0; g < 4; ++g) { bvA[g] = b1[g * H_ + hl0]; bvB[g] = b1[g * H_ + hl0 + 1]; }
    }

    const u64* qa  = reinterpret_cast<const u64*>(l0f) + lane;
    const u64* qbf = reinterpret_cast<const u64*>(l1f);
    const u64* qpf = reinterpret_cast<const u64*>(pf);

    __syncthreads();

    for (int p = 0; p < T_; ++p) {
        f32x4 acc0 = {0.f, 0.f, 0.f, 0.f}, acc1 = {0.f, 0.f, 0.f, 0.f};
        bf16x8 s0[8], s1[8], s2[8];
        f32x4 pa0, pa1;

        if (wave == 7) {
            if (isL0)       { pollge(qa, p);     pollge32(qpf, p - 3, lane); }
            else if (!isK1) { pollge(qa, p + 1); pollge32(qbf, p - 3, lane); }
            else {
                pollge32(qbf, p, lane);
                const unsigned* pfj = pf + j;
                while ((int)__hip_atomic_load(pfj, __ATOMIC_RELAXED, __HIP_MEMORY_SCOPE_AGENT) < p + 1)
                    __builtin_amdgcn_s_sleep(1);
                __builtin_amdgcn_sched_barrier(0);
            }
        } else if (isL0 && sub == 0) {
            const float* xr = x + ((size_t)rowA * T_ + p) * D_ + kg * 8;
            f32x4 xs[16]; bf16x8 fr[8];
            const int cb0 = r16 * 3072, cb1 = cb0 + 16 * 3072;
            ldx16(xs, xr);
            VMWAIT(0);
            #pragma unroll
            for (int q = 0; q < 8; ++q) fr[q] = cvt8(xs[2 * q], xs[2 * q + 1]);
            ldx16(xs, xr + 256);
            mfma2(fr, lds, cb0, cb1, kg * 16, sw, acc0, acc1);
            VMWAIT(0);
            #pragma unroll
            for (int q = 0; q < 8; ++q) fr[q] = cvt8(xs[2 * q], xs[2 * q + 1]);
            mfma2(fr, lds, cb0, cb1, 512 + kg * 16, sw, acc0, acc1);
        }
        __syncthreads();

        if (isL0) {
            const int cb0 = r16 * 3072, cb1 = cb0 + 16 * 3072;
            const u16* hb = h0w + (size_t)((p - 1) & 3) * BH + kg * 512 + rowA * 8;
            if (sub == 0) {
                ld8_oct(s2, hb);
                ld8_oct(s0, hb + 16384);
                VMWAIT(8); mfma2(s2, lds, cb0, cb1, 1024 + kg * 16,       sw, acc0, acc1);
                VMWAIT(0); mfma2(s0, lds, cb0, cb1, 1024 + 512 + kg * 16, sw, acc0, acc1);
            } else {
                ld8_oct(s0, hb + 2 * 16384);
                ld8_oct(s1, hb + 3 * 16384);
                VMWAIT(8); mfma2(s0, lds, cb0, cb1, 1024 + 1024 + kg * 16, sw, acc0, acc1);
                VMWAIT(0); mfma2(s1, lds, cb0, cb1, 1024 + 1536 + kg * 16, sw, acc0, acc1);
            }
            #pragma unroll
            for (int r = 0; r < 4; ++r) {
                const int row = m * 16 + kg * 4 + r;
                scr[(sub * 64 + row) * 36 + r16]      = acc0[r];
                scr[(sub * 64 + row) * 36 + 16 + r16] = acc1[r];
            }
            __syncthreads();

            const float4 ga = *reinterpret_cast<const float4*>(&scr[prow * 36 + 4 * ph]);
            const float4 gb = *reinterpret_cast<const float4*>(&scr[(64 + prow) * 36 + 4 * ph]);
            const float gi = ga.x + gb.x + bvA[0];
            const float gf = ga.y + gb.y + bvA[1];
            const float gg = ga.z + gb.z + bvA[2];
            const float go = ga.w + gb.w + bvA[3];
            const float cn = sigm(gf) * creg0 + sigm(gi) * ftanh(gg);
            const float hn = sigm(go) * ftanh(cn);
            creg0 = cn;
            hstg[tid] = f2bf(hn);
            __syncthreads();
            if (wave == 7) {
                u16x8 hv = *reinterpret_cast<const u16x8*>(hstg + 8 * lane);
                u16* dst = h0w + (size_t)(p & 3) * BH + bid * 512 + lane * 8;
                asm volatile("global_store_dwordx4 %0, %1, off sc0 sc1" :: "v"(dst), "v"(hv) : "memory");
                VMWAIT(0);
                if (lane == 0)
                    __hip_atomic_store(l0f + bid, (unsigned)(p + 1),
                                       __ATOMIC_RELAXED, __HIP_MEMORY_SCOPE_AGENT);
            }
            if (p == T_ - 1) {
                const int hidx = prow * H_ + bid * 8 + ph;
                out[BTH + hidx] = cn;                                // c0
                out[BTH + BH + hidx] = hn;                           // h0
            }
        } else {
            if (isK1) {
                const float* pa = prt + (size_t)(p & 3) * 262144 + j * 4096 + prow * 64 + ph * 8;
                asm volatile("global_load_dwordx4 %0, %2, off sc0 sc1\n\t"
                             "global_load_dwordx4 %1, %2, off offset:16 sc0 sc1"
                             : "=&v"(pa0), "=&v"(pa1) : "v"(pa));
            }
            const u16* ab = (isK1 ? h1w + (size_t)((p - 1) & 1) * BH
                                  : h0w + (size_t)(p & 3) * BH) + kg * 512 + rowA * 8;
            const int cb0 = (sub * 32 + r16) * 2048, cb1 = cb0 + 16 * 2048;
            ld8_oct(s0, ab);
            ld8_oct(s1, ab + 16384);
            ld8_oct(s2, ab + 2 * 16384);
            VMWAIT(16); mfma2(s0, lds, cb0, cb1, kg * 16,        sw, acc0, acc1);
            ld8_oct(s0, ab + 3 * 16384);
            VMWAIT(16); mfma2(s1, lds, cb0, cb1, 512 + kg * 16,  sw, acc0, acc1);
            VMWAIT(8);  mfma2(s2, lds, cb0, cb1, 1024 + kg * 16, sw, acc0, acc1);
            VMWAIT(0);  mfma2(s0, lds, cb0, cb1, 1536 + kg * 16, sw, acc0, acc1);

            if (!isK1) {  // K0: publish partials + flag
                float* pp = prt + (size_t)(p & 3) * 262144 + j * 4096
                          + (size_t)(m * 16 + kg * 4) * 64 + sub * 32 + r16;
                #pragma unroll
                for (int r = 0; r < 4; ++r) {
                    asm volatile("global_store_dword %0, %1, off sc0 sc1"
                                 :: "v"(pp + r * 64), "v"(acc0[r]) : "memory");
                    asm volatile("global_store_dword %0, %1, off sc0 sc1"
                                 :: "v"(pp + r * 64 + 16), "v"(acc1[r]) : "memory");
                }
                VMWAIT(0);
                __syncthreads();
                if (tid == 0)
                    __hip_atomic_store(pf + j, (unsigned)(p + 1),
                                       __ATOMIC_RELAXED, __HIP_MEMORY_SCOPE_AGENT);
            } else {      // K1: combine + pointwise + publish
                #pragma unroll
                for (int r = 0; r < 4; ++r) {
                    const int row = m * 16 + kg * 4 + r;
                    scr[row * 76 + sub * 32 + r16]      = acc0[r];
                    scr[row * 76 + sub * 32 + 16 + r16] = acc1[r];
                }
                __syncthreads();
                const float4 g0 = *reinterpret_cast<const float4*>(&scr[prow * 76 + ph * 8]);
                const float4 g1 = *reinterpret_cast<const float4*>(&scr[prow * 76 + ph * 8 + 4]);
                const float gi0 = g0.x + pa0[0] + bvA[0], gf0 = g0.y + pa0[1] + bvA[1];
                const float gg0 = g0.z + pa0[2] + bvA[2], go0 = g0.w + pa0[3] + bvA[3];
                const float gi1 = g1.x + pa1[0] + bvB[0], gf1 = g1.y + pa1[1] + bvB[1];
                const float gg1 = g1.z + pa1[2] + bvB[2], go1 = g1.w + pa1[3] + bvB[3];
                const float cn0 = sigm(gf0) * creg0 + sigm(gi0) * ftanh(gg0);
                const float hn0 = sigm(go0) * ftanh(cn0);
                const float cn1 = sigm(gf1) * creg1 + sigm(gi1) * ftanh(gg1);
                const float hn1 = sigm(go1) * ftanh(cn1);
                creg0 = cn0; creg1 = cn1;
                const int hl0 = 2 * ph, hl1 = hl0 + 1;
                hstg[(hl0 >> 3) * 512 + prow * 8 + (hl0 & 7)] = f2bf(hn0);
                hstg[(hl1 >> 3) * 512 + prow * 8 + (hl1 & 7)] = f2bf(hn1);
                __syncthreads();
                if (wave == 7) {
                    u16x8 ha = *reinterpret_cast<const u16x8*>(hstg + lane * 16);
                    u16x8 hbv = *reinterpret_cast<const u16x8*>(hstg + lane * 16 + 8);
                    u16* dst = h1w + (size_t)(p & 1) * BH + j * 1024 + lane * 16;
                    asm volatile("global_store_dwordx4 %0, %1, off sc0 sc1\n\t"
                                 "global_store_dwordx4 %0, %2, off offset:16 sc0 sc1"
                                 :: "v"(dst), "v"(ha), "v"(hbv) : "memory");
                    VMWAIT(0);
                    if (lane == 0)
                        __hip_atomic_store(l1f + j, (unsigned)(p + 1),
                                           __ATOMIC_RELAXED, __HIP_MEMORY_SCOPE_AGENT);
                }
                const int gc0 = 16 * j + hl0;
                float2 yv; yv.x = hn0; yv.y = hn1;
                *reinterpret_cast<float2*>(&out[((size_t)prow * T_ + p) * H_ + gc0]) = yv;
                if (p == T_ - 1) {
                    out[BTH + 2 * BH + prow * H_ + gc0]     = cn0;   // c1
                    out[BTH + 2 * BH + prow * H_ + gc0 + 1] = cn1;
                    out[BTH + 3 * BH + prow * H_ + gc0]     = hn0;   // h1
                    out[BTH + 3 * BH + prow * H_ + gc0 + 1] = hn1;
                }
            }
        }
    }
}

extern "C" void kernel_launch(void* const* d_in, const int* in_sizes, int n_in,
                              void* d_out, int out_size, void* d_ws, size_t ws_size,
                              hipStream_t stream) {
    const float* x   = (const float*)d_in[0];
    const float* Wx0 = (const float*)d_in[1];
    const float* Wh0 = (const float*)d_in[2];
    const float* b0  = (const float*)d_in[3];
    const float* Wx1 = (const float*)d_in[4];
    const float* Wh1 = (const float*)d_in[5];
    const float* b1  = (const float*)d_in[6];
    float* out = (float*)d_out;
    char* ws = (char*)d_ws;

    // workspace layout (bytes), ~34.3 MB
    u16* Wx0T = (u16*)(ws);               //  4,194,304
    u16* WT0  = (u16*)(ws + 4194304);     //  8,388,608
    u16* WT1  = (u16*)(ws + 12582912);    // 16,777,216 -> ends 29,360,128
    unsigned int* l0f = (unsigned int*)(ws + 29360128);  // 512 B
    unsigned int* l1f = (unsigned int*)(ws + 29360640);  // 256 B
    unsigned int* pf  = (unsigned int*)(ws + 29360896);  // 256 B (+896 pad)
    u16* h0w  = (u16*)(ws + 29362176);    // 524,288
    u16* h1w  = (u16*)(ws + 29886464);    // 262,144
    float* prt = (float*)(ws + 30148608); // 4,194,304 -> ends 34,342,912

    const int LDS_BYTES = 64 * 2048 + 19456 + 2048;   // 152,576
    (void)hipFuncSetAttribute((const void*)lstm_persist,
                        hipFuncAttributeMaxDynamicSharedMemorySize, LDS_BYTES);

    (void)hipMemsetAsync(ws + 29360128, 0, 788480, stream);

    dim3 blk(32, 8);
    transp<<<dim3(128, 16), blk, 0, stream>>>(Wx0, Wx0T, 4096, 512, 0);
    transp<<<dim3(128, 32), blk, 0, stream>>>(Wh0, WT0, 4096, 1024, 0);
    transp<<<dim3(128, 32), blk, 0, stream>>>(Wx1, WT1, 4096, 2048, 0);
    transp<<<dim3(128, 32), blk, 0, stream>>>(Wh1, WT1, 4096, 2048, 1024);

    lstm_persist<<<256, 512, LDS_BYTES, stream>>>(x, Wx0T, WT0, WT1, b0, b1,
                                                  l0f, l1f, pf, h0w, h1w, prt, out);
}

// Round 13
// 7471.902 us; speedup vs baseline: 2.2861x; 2.2861x over previous
//
#include <hip/hip_runtime.h>
#include <hip/hip_bf16.h>
#include <cstdint>

#define B_ 64
#define T_ 1024
#define D_ 512
#define H_ 1024

typedef unsigned short u16;
typedef unsigned long long u64;
typedef __attribute__((ext_vector_type(4))) float f32x4;
typedef __attribute__((ext_vector_type(8))) short bf16x8;   // 8 bf16 in 4 VGPRs
typedef __attribute__((ext_vector_type(8))) u16 u16x8;

#define VMWAIT(N) do { asm volatile("s_waitcnt vmcnt(" #N ")" ::: "memory"); \
                       __builtin_amdgcn_sched_barrier(0); } while (0)

__device__ __forceinline__ u16 f2bf(float f) {
    uint32_t u = __float_as_uint(f);
    uint32_t r = (u + 0x7FFFu + ((u >> 16) & 1u)) >> 16;   // RNE
    return (u16)r;
}
__device__ __forceinline__ float sigm(float x)  { return 1.f / (1.f + __expf(-x)); }
__device__ __forceinline__ float ftanh(float x) { return 1.f - 2.f / (__expf(2.f * x) + 1.f); }

// ---- x fp32 -> bf16 (vectorized) ----
__global__ __launch_bounds__(256) void pack_x(const float* __restrict__ x, u16* __restrict__ xb) {
    size_t i = ((size_t)blockIdx.x * 256 + threadIdx.x) * 8;
    float4 a = *reinterpret_cast<const float4*>(x + i);
    float4 c = *reinterpret_cast<const float4*>(x + i + 4);
    u16x8 v;
    v[0] = f2bf(a.x); v[1] = f2bf(a.y); v[2] = f2bf(a.z); v[3] = f2bf(a.w);
    v[4] = f2bf(c.x); v[5] = f2bf(c.y); v[6] = f2bf(c.z); v[7] = f2bf(c.w);
    *reinterpret_cast<u16x8*>(xb + i) = v;
}

// ---- W [K][N] fp32 -> WT [N][dstLD] bf16 at column offset koff ----
__global__ __launch_bounds__(256) void transp(const float* __restrict__ src, u16* __restrict__ dst,
                                              int N, int dstLD, int koff) {
    __shared__ float tile[32][33];
    int n0 = blockIdx.x * 32, k0 = blockIdx.y * 32;
    int tx = threadIdx.x, ty = threadIdx.y;   // 32 x 8
    #pragma unroll
    for (int i = 0; i < 4; ++i)
        tile[ty + 8 * i][tx] = src[(size_t)(k0 + ty + 8 * i) * N + n0 + tx];
    __syncthreads();
    #pragma unroll
    for (int i = 0; i < 4; ++i) {
        int n = n0 + ty + 8 * i;
        dst[(size_t)n * dstLD + koff + k0 + tx] = f2bf(tile[tx][ty + 8 * i]);
    }
}

// 8 x-fragments, row-major (stride 64B), plain cached
__device__ __forceinline__ void ld8_pln(bf16x8* s, const u16* p) {
    asm volatile(
        "global_load_dwordx4 %0, %8, off\n\t"
        "global_load_dwordx4 %1, %8, off offset:64\n\t"
        "global_load_dwordx4 %2, %8, off offset:128\n\t"
        "global_load_dwordx4 %3, %8, off offset:192\n\t"
        "global_load_dwordx4 %4, %8, off offset:256\n\t"
        "global_load_dwordx4 %5, %8, off offset:320\n\t"
        "global_load_dwordx4 %6, %8, off offset:384\n\t"
        "global_load_dwordx4 %7, %8, off offset:448"
        : "=&v"(s[0]), "=&v"(s[1]), "=&v"(s[2]), "=&v"(s[3]),
          "=&v"(s[4]), "=&v"(s[5]), "=&v"(s[6]), "=&v"(s[7])
        : "v"(p));
}
// 8 h-fragments, octet-major layout (stride 4096B), coherent (MALL-direct)
__device__ __forceinline__ void ld8_oct(bf16x8* s, const u16* base) {
    #pragma unroll
    for (int j = 0; j < 8; ++j) {
        const u16* pj = base + j * 2048;
        asm volatile("global_load_dwordx4 %0, %1, off sc0 sc1" : "=&v"(s[j]) : "v"(pj));
    }
}

__device__ __forceinline__ void mfma_chunk(const bf16x8* st, const char* lds, int kb0, int K2,
                                           int r16, int sw, f32x4& acc0, f32x4& acc1) {
    #pragma unroll
    for (int j = 0; j < 8; ++j) {
        const int kb = kb0 + j * 64;
        bf16x8 w0 = *reinterpret_cast<const bf16x8*>(lds + ((r16 * K2 + kb) ^ sw));
        bf16x8 w1 = *reinterpret_cast<const bf16x8*>(lds + (((r16 + 16) * K2 + kb) ^ sw));
        acc0 = __builtin_amdgcn_mfma_f32_16x16x32_bf16(st[j], w0, acc0, 0, 0, 0);
        acc1 = __builtin_amdgcn_mfma_f32_16x16x32_bf16(st[j], w1, acc1, 0, 0, 0);
    }
}

// wave-wide poll: lane l watches flag pair q[l]; returns when ALL 128 flags >= t
__device__ __forceinline__ void pollge(const u64* q, int t) {
    if (t <= 0) return;
    for (;;) {
        u64 v = __hip_atomic_load(q, __ATOMIC_RELAXED, __HIP_MEMORY_SCOPE_AGENT);
        bool ok = ((int)(unsigned)v >= t) && ((int)(unsigned)(v >> 32) >= t);
        if (__all(ok)) break;
        __builtin_amdgcn_s_sleep(1);
    }
    __builtin_amdgcn_sched_barrier(0);
}

// ============ persistent fused 2-layer LSTM (r7 + L1 h0-half hoisted pre-barrier) ======
// 256 blocks x 512 threads, 1 block/CU. Flags: flg[0..128)=L0, flg[128..256)=L1.
// h rings OCTET-MAJOR: h[slot][col/8][row][8] u16; publish/reads sc0sc1 (MALL-direct).
// L1 kh0 waves self-poll qa>=p+1 (pre-satisfied: L0 runs ~3 ahead) and do the ENTIRE
// h0-half GEMM pre-barrier — overlapping the critical h1 publish/notice legs. Post-flag
// burst halves (256KB -> 128KB per L1 block). Wave7 polls only qb. Everything else = r7.
extern "C" __global__ void __launch_bounds__(512, 2) lstm_persist(
    const u16* __restrict__ xb, const u16* __restrict__ Wx0T,
    const u16* __restrict__ WT0, const u16* __restrict__ WT1,
    const float* __restrict__ b0, const float* __restrict__ b1,
    unsigned int* __restrict__ flg,
    u16* __restrict__ h0r, u16* __restrict__ h1r,
    float* __restrict__ out)
{
    extern __shared__ char lds[];
    const int tid = threadIdx.x;
    const int bid = blockIdx.x;
    const bool isL1 = bid >= 128;
    const int oct = isL1 ? bid - 128 : bid;        // owned col-octet
    const int bh = oct * 8;                        // first owned h-col
    const int KL = isL1 ? 2048 : 1536;
    const int K2 = KL * 2;                          // LDS col stride (bytes)
    float* scr = (float*)(lds + 32 * K2);           // [2][64][36] f32 partial gates
    u16* hstg = (u16*)(lds + 32 * K2 + 18432);      // 512 u16 staged h

    // ---- stage weight slice into LDS (XOR-swizzled) ----
    const int KO = KL / 8;
    for (int idx = tid; idx < 32 * KO; idx += 512) {
        const int c = idx / KO, ko = idx - c * KO;
        const int g = c & 3, h = c >> 2;
        const int n = g * H_ + bh + h;              // flax gate order i,f,g,o
        const int k = ko * 8;
        u16x8 v;
        if (isL1)            v = *reinterpret_cast<const u16x8*>(WT1  + (size_t)n * 2048 + k);
        else if (k < 512)    v = *reinterpret_cast<const u16x8*>(Wx0T + (size_t)n * 512  + k);
        else                 v = *reinterpret_cast<const u16x8*>(WT0  + (size_t)n * 1024 + (k - 512));
        int byte = c * K2 + k * 2;
        byte ^= ((c & 7) << 4);
        *reinterpret_cast<u16x8*>(lds + byte) = v;
    }

    const int wave = tid >> 6, lane = tid & 63;
    const int r16 = lane & 15, kg = lane >> 4;
    const int m  = wave & 3;        // M-tile
    const int kh = wave >> 2;       // K-half
    const int rowA = m * 16 + r16;
    const int prow = tid >> 3, ph = tid & 7;

    float bv0, bv1, bv2, bv3;
    {
        const float* bias = isL1 ? b1 : b0;
        bv0 = bias[bh + ph];          bv1 = bias[H_ + bh + ph];
        bv2 = bias[2 * H_ + bh + ph]; bv3 = bias[3 * H_ + bh + ph];
    }
    float creg = 0.f;

    const int BH = B_ * H_;                          // u16 per h slot
    const size_t BTH = (size_t)B_ * T_ * H_;
    const int sw = ((r16 & 7) << 4);
    const u64* qa = reinterpret_cast<const u64*>(flg) + lane;         // L0 flags
    const u64* qb = reinterpret_cast<const u64*>(flg + 128) + lane;   // L1 flags

    __syncthreads();   // weights staged

    for (int p = 0; p < T_; ++p) {
        f32x4 acc0 = {0.f, 0.f, 0.f, 0.f}, acc1 = {0.f, 0.f, 0.f, 0.f};
        bf16x8 s0[8], s1[8], s2[8];

        // ---- pre-barrier phase ----
        if (wave == 7) {
            if (!isL1) { pollge(qa, p);     pollge(qb, p - 3); }   // h0 deps + ring guard
            else       { pollge(qb, p); }                          // critical h1 dep only
        } else if (!isL1 && kh == 0) {
            // L0: flag-independent x-part
            const u16* xrow = xb + ((size_t)rowA * T_ + p) * D_ + kg * 8;
            ld8_pln(s0, xrow);
            ld8_pln(s1, xrow + 256);
            VMWAIT(8); mfma_chunk(s0, lds, kg * 16,       K2, r16, sw, acc0, acc1);
            VMWAIT(0); mfma_chunk(s1, lds, 512 + kg * 16, K2, r16, sw, acc0, acc1);
        } else if (isL1 && kh == 0) {
            // L1 h0-half: gated on qa>=p+1 (normally pre-satisfied -> instant poll)
            pollge(qa, p + 1);
            const u16* ab = h0r + (size_t)(p & 3) * BH + kg * 512 + rowA * 8;
            const int b0k = kg * 16;
            ld8_oct(s0, ab);
            ld8_oct(s1, ab + 16384);
            ld8_oct(s2, ab + 2 * 16384);
            VMWAIT(16); mfma_chunk(s0, lds, b0k,        K2, r16, sw, acc0, acc1);
            ld8_oct(s0, ab + 3 * 16384);
            VMWAIT(16); mfma_chunk(s1, lds, b0k + 512,  K2, r16, sw, acc0, acc1);
            VMWAIT(8);  mfma_chunk(s2, lds, b0k + 1024, K2, r16, sw, acc0, acc1);
            VMWAIT(0);  mfma_chunk(s0, lds, b0k + 1536, K2, r16, sw, acc0, acc1);
            #pragma unroll
            for (int r = 0; r < 4; ++r) {               // scr kh0 half (safe pre-barrier)
                const int row = m * 16 + kg * 4 + r;
                scr[row * 36 + r16]      = acc0[r];
                scr[row * 36 + 16 + r16] = acc1[r];
            }
        }
        __syncthreads();

        // ---- post-barrier: critical-path loads + MFMA ----
        if (!isL1) {
            const u16* hb = h0r + (size_t)((p - 1) & 3) * BH + kg * 512 + rowA * 8;
            if (kh == 0) {          // h chunks 0,1 (k 512..1024 of [x;h])
                ld8_oct(s2, hb);
                ld8_oct(s0, hb + 16384);
                VMWAIT(8); mfma_chunk(s2, lds, 1024 + kg * 16,       K2, r16, sw, acc0, acc1);
                VMWAIT(0); mfma_chunk(s0, lds, 1024 + 512 + kg * 16, K2, r16, sw, acc0, acc1);
            } else {                // h chunks 2,3
                ld8_oct(s0, hb + 2 * 16384);
                ld8_oct(s1, hb + 3 * 16384);
                VMWAIT(8); mfma_chunk(s0, lds, 1024 + 1024 + kg * 16, K2, r16, sw, acc0, acc1);
                VMWAIT(0); mfma_chunk(s1, lds, 1024 + 1536 + kg * 16, K2, r16, sw, acc0, acc1);
            }
            #pragma unroll
            for (int r = 0; r < 4; ++r) {
                const int row = m * 16 + kg * 4 + r;     // D: col=lane&15, row=kg*4+r
                scr[(kh * 64 + row) * 36 + r16]      = acc0[r];
                scr[(kh * 64 + row) * 36 + 16 + r16] = acc1[r];
            }
        } else if (kh == 1) {
            // L1 h1-half: the true critical leg (flag just flipped)
            const u16* ab = h1r + (size_t)((p - 1) & 1) * BH + kg * 512 + rowA * 8;
            const int b0k = 2048 + kg * 16;
            ld8_oct(s0, ab);
            ld8_oct(s1, ab + 16384);
            ld8_oct(s2, ab + 2 * 16384);
            VMWAIT(16); mfma_chunk(s0, lds, b0k,        K2, r16, sw, acc0, acc1);
            ld8_oct(s0, ab + 3 * 16384);
            VMWAIT(16); mfma_chunk(s1, lds, b0k + 512,  K2, r16, sw, acc0, acc1);
            VMWAIT(8);  mfma_chunk(s2, lds, b0k + 1024, K2, r16, sw, acc0, acc1);
            VMWAIT(0);  mfma_chunk(s0, lds, b0k + 1536, K2, r16, sw, acc0, acc1);
            #pragma unroll
            for (int r = 0; r < 4; ++r) {
                const int row = m * 16 + kg * 4 + r;
                scr[(64 + row) * 36 + r16]      = acc0[r];
                scr[(64 + row) * 36 + 16 + r16] = acc1[r];
            }
        }
        __syncthreads();

        // ---- pointwise ----
        const float4 ga = *reinterpret_cast<const float4*>(&scr[prow * 36 + 4 * ph]);
        const float4 gb = *reinterpret_cast<const float4*>(&scr[(64 + prow) * 36 + 4 * ph]);
        const float gi = ga.x + gb.x + bv0;
        const float gf = ga.y + gb.y + bv1;
        const float gg = ga.z + gb.z + bv2;
        const float go = ga.w + gb.w + bv3;
        const float cn = sigm(gf) * creg + sigm(gi) * ftanh(gg);
        const float hn = sigm(go) * ftanh(cn);
        creg = cn;
        hstg[tid] = f2bf(hn);
        __syncthreads();

        // ---- wave7: coalesced coherent publish (1KB) + flag release ----
        if (wave == 7) {
            u16x8 hv = *reinterpret_cast<const u16x8*>(hstg + 8 * lane);  // row=lane, 8 cols
            u16* dst = (isL1 ? h1r + (size_t)(p & 1) * BH : h0r + (size_t)(p & 3) * BH)
                       + oct * 512 + lane * 8;
            asm volatile("global_store_dwordx4 %0, %1, off sc0 sc1" :: "v"(dst), "v"(hv) : "memory");
            VMWAIT(0);
            if (lane == 0)
                __hip_atomic_store(flg + bid, (unsigned)(p + 1),
                                   __ATOMIC_RELAXED, __HIP_MEMORY_SCOPE_AGENT);
        }

        // ---- slow HBM outputs after the release ----
        const int hidx = prow * H_ + bh + ph;
        if (isL1) {
            out[((size_t)prow * T_ + p) * H_ + bh + ph] = hn;        // y
            if (p == T_ - 1) {
                out[BTH + 2 * BH + hidx] = cn;                       // c1
                out[BTH + 3 * BH + hidx] = hn;                       // h1
            }
        } else if (p == T_ - 1) {
            out[BTH + hidx] = cn;                                    // c0
            out[BTH + BH + hidx] = hn;                               // h0
        }
    }
}

extern "C" void kernel_launch(void* const* d_in, const int* in_sizes, int n_in,
                              void* d_out, int out_size, void* d_ws, size_t ws_size,
                              hipStream_t stream) {
    const float* x   = (const float*)d_in[0];
    const float* Wx0 = (const float*)d_in[1];
    const float* Wh0 = (const float*)d_in[2];
    const float* b0  = (const float*)d_in[3];
    const float* Wx1 = (const float*)d_in[4];
    const float* Wh1 = (const float*)d_in[5];
    const float* b1  = (const float*)d_in[6];
    float* out = (float*)d_out;
    char* ws = (char*)d_ws;

    // workspace layout (bytes) — identical to round 7 (proven)
    u16* xb   = (u16*)(ws);               // 67,108,864
    u16* Wx0T = (u16*)(ws + 67108864);    //  4,194,304
    u16* WT0  = (u16*)(ws + 71303168);    //  8,388,608
    u16* WT1  = (u16*)(ws + 79691776);    // 16,777,216 -> ends 96,468,992
    unsigned int* flg = (unsigned int*)(ws + 96468992);  // 1024 B (+512 pad)
    u16* h0r  = (u16*)(ws + 96470016);    // 4 * 131072 = 524,288
    u16* h1r  = (u16*)(ws + 96994304);    // 2 * 131072 = 262,144

    const int LDS_BYTES = 32 * 2048 * 2 + 18432 + 1024;   // 150,528
    (void)hipFuncSetAttribute((const void*)lstm_persist,
                        hipFuncAttributeMaxDynamicSharedMemorySize, LDS_BYTES);

    // zero flags + pad + h rings
    (void)hipMemsetAsync(ws + 96468992, 0, 787456, stream);

    pack_x<<<16384, 256, 0, stream>>>(x, xb);
    dim3 blk(32, 8);
    transp<<<dim3(128, 16), blk, 0, stream>>>(Wx0, Wx0T, 4096, 512, 0);
    transp<<<dim3(128, 32), blk, 0, stream>>>(Wh0, WT0, 4096, 1024, 0);
    transp<<<dim3(128, 32), blk, 0, stream>>>(Wx1, WT1, 4096, 2048, 0);
    transp<<<dim3(128, 32), blk, 0, stream>>>(Wh1, WT1, 4096, 2048, 1024);

    lstm_persist<<<256, 512, LDS_BYTES, stream>>>(xb, Wx0T, WT0, WT1, b0, b1,
                                                  flg, h0r, h1r, out);
}